// Round 5
// baseline (138.018 us; speedup 1.0000x reference)
//
#include <hip/hip_runtime.h>
#include <hip/hip_cooperative_groups.h>

namespace cg = cooperative_groups;

// prediction [10,5,10,1024,100] f32, label [1024] int.
constexpr int C = 100;
constexpr int B = 1024;
constexpr int NROWS = 10 * 5 * 10 * 1024;        // 512000 rows of C floats
constexpr float MT_SUM = 0.6f;                   // m + T
constexpr float M_MARGIN = 0.1f;
constexpr int ROWS_PER_TILE = 64;                // 256 threads / 4 lanes-per-row
constexpr int NTILES = NROWS / ROWS_PER_TILE;    // 8000
constexpr int GRID = 1024;                       // 4 blocks/CU, guaranteed co-resident

__global__ __launch_bounds__(256, 4) void fused_loss_kernel(
    const float* __restrict__ pred,
    const int* __restrict__ lab,
    float* __restrict__ partial,
    float* __restrict__ out)
{
    const int t = threadIdx.x;
    const int g = t & 3;          // lane within 4-lane row group
    const int rr = t >> 2;        // row within tile (0..63)

    float lsum = 0.0f;
    for (int tile = blockIdx.x; tile < NTILES; tile += GRID) {
        const int r = tile * ROWS_PER_TILE + rr;
        const int y = lab[r & (B - 1)];
        const float4* row = reinterpret_cast<const float4*>(pred + (size_t)r * C);
        float fy = -1e30f;        // sentinel; exactly one lane in group finds y
        float mx = -1e30f;
#pragma unroll
        for (int k = 0; k < 7; ++k) {
            const int fi = g + 4 * k;   // group covers 64B contiguous
            if (fi < 25) {
                const float4 v = row[fi];
                const int c0 = 4 * fi;
                const bool e0 = (c0 + 0 == y), e1 = (c0 + 1 == y),
                           e2 = (c0 + 2 == y), e3 = (c0 + 3 == y);
                fy = e0 ? v.x : fy;  mx = fmaxf(mx, e0 ? -1e30f : v.x);
                fy = e1 ? v.y : fy;  mx = fmaxf(mx, e1 ? -1e30f : v.y);
                fy = e2 ? v.z : fy;  mx = fmaxf(mx, e2 ? -1e30f : v.z);
                fy = e3 ? v.w : fy;  mx = fmaxf(mx, e3 ? -1e30f : v.w);
            }
        }
        // reduce fy / mx across the aligned 4-lane group
        fy = fmaxf(fy, __shfl_xor(fy, 1, 64));
        fy = fmaxf(fy, __shfl_xor(fy, 2, 64));
        mx = fmaxf(mx, __shfl_xor(mx, 1, 64));
        mx = fmaxf(mx, __shfl_xor(mx, 2, 64));
        lsum += fmaxf(MT_SUM - fy, 0.0f) + fmaxf(M_MARGIN + mx, 0.0f);
    }

    // block reduction (each row counted by 4 lanes -> 0.25 weight)
#pragma unroll
    for (int off = 32; off > 0; off >>= 1)
        lsum += __shfl_down(lsum, off, 64);
    __shared__ float ws[4];
    if ((t & 63) == 0) ws[t >> 6] = lsum;
    __syncthreads();
    if (t == 0) partial[blockIdx.x] = (ws[0] + ws[1] + ws[2] + ws[3]) * 0.25f;

    cg::this_grid().sync();

    if (blockIdx.x == 0) {
        // 1024 partials, 256 threads
        float s = partial[t] + partial[t + 256] + partial[t + 512] + partial[t + 768];
#pragma unroll
        for (int off = 32; off > 0; off >>= 1)
            s += __shfl_down(s, off, 64);
        __shared__ float ws2[4];
        if ((t & 63) == 0) ws2[t >> 6] = s;
        __syncthreads();
        if (t == 0)
            out[0] = (ws2[0] + ws2[1] + ws2[2] + ws2[3]) * (1.0f / (float)NROWS);
    }
}

extern "C" void kernel_launch(void* const* d_in, const int* in_sizes, int n_in,
                              void* d_out, int out_size, void* d_ws, size_t ws_size,
                              hipStream_t stream) {
    const float* pred = (const float*)d_in[0];
    const int* lab = (const int*)d_in[1];
    float* out = (float*)d_out;
    float* partial = (float*)d_ws;

    void* args[] = {(void*)&pred, (void*)&lab, (void*)&partial, (void*)&out};
    hipLaunchCooperativeKernel((void*)fused_loss_kernel,
                               dim3(GRID), dim3(256), args, 0, stream);
}

// Round 6
// 36.503 us; speedup vs baseline: 3.7810x; 3.7810x over previous
//
#include <hip/hip_runtime.h>

// prediction [10,5,10,1024,100] f32, label [1024] int.
constexpr int C = 100;
constexpr int B = 1024;
constexpr int NROWS = 10 * 5 * 10 * 1024;        // 512000 rows of C floats
constexpr float MT_SUM = 0.6f;                   // m + T
constexpr float M_MARGIN = 0.1f;
constexpr int ROWS_PER_BLOCK = 64;               // 256 threads / 4 lanes-per-row
constexpr int NBLOCKS = NROWS / ROWS_PER_BLOCK;  // 8000

__device__ __forceinline__ void upd(float val, int c, int y, float& fy, float& mx) {
    const bool ok = (unsigned)c < (unsigned)C;   // inside this row?
    const bool ey = (c == y);
    fy = ey ? val : fy;
    mx = fmaxf(mx, (ok && !ey) ? val : -1e30f);
}

__global__ __launch_bounds__(256) void loss_rows_kernel(
    const float* __restrict__ pred,
    const int* __restrict__ lab,
    float* __restrict__ partial)
{
    const int t = threadIdx.x;
    const int g = t & 3;            // lane within 4-lane row group
    const int rr = t >> 2;          // row within block tile
    const int r = blockIdx.x * ROWS_PER_BLOCK + rr;
    const int y = lab[r & (B - 1)];

    // Row r = float4s [25r, 25r+25). Aligned cover: base (25r)&~3, 28 float4s.
    // off = (25r) mod 4 = r mod 4. Cover stays inside the 4-row 1600B chunk -> no OOB.
    const int off = r & 3;
    const size_t f0 = (size_t)r * 25;
    const float4* base = reinterpret_cast<const float4*>(pred) + (f0 - off) + g;

    float fy = -1e30f;              // exactly one lane in group finds y
    float mx = -1e30f;
#pragma unroll
    for (int k = 0; k < 7; ++k) {
        const float4 v = base[4 * k];              // aligned 64B per 4-lane group
        const int c0 = (g + 4 * k - off) * 4;      // class index of v.x (may be <0 or >=C)
        upd(v.x, c0 + 0, y, fy, mx);
        upd(v.y, c0 + 1, y, fy, mx);
        upd(v.z, c0 + 2, y, fy, mx);
        upd(v.w, c0 + 3, y, fy, mx);
    }
    // reduce fy / mx across the aligned 4-lane group
    fy = fmaxf(fy, __shfl_xor(fy, 1, 64));
    fy = fmaxf(fy, __shfl_xor(fy, 2, 64));
    mx = fmaxf(mx, __shfl_xor(mx, 1, 64));
    mx = fmaxf(mx, __shfl_xor(mx, 2, 64));

    float l = fmaxf(MT_SUM - fy, 0.0f) + fmaxf(M_MARGIN + mx, 0.0f);

    // wave sum reduction; each row counted by 4 lanes -> 0.25 weight
#pragma unroll
    for (int offs = 32; offs > 0; offs >>= 1)
        l += __shfl_down(l, offs, 64);
    __shared__ float ws[4];
    if ((t & 63) == 0) ws[t >> 6] = l;
    __syncthreads();
    if (t == 0)
        partial[blockIdx.x] = (ws[0] + ws[1] + ws[2] + ws[3]) * 0.25f;
}

__global__ __launch_bounds__(1024) void reduce_final_kernel(
    const float* __restrict__ partial, int n, float* __restrict__ out)
{
    float s = 0.0f;
    for (int i = threadIdx.x; i < n; i += 1024) s += partial[i];
#pragma unroll
    for (int offs = 32; offs > 0; offs >>= 1)
        s += __shfl_down(s, offs, 64);
    __shared__ float ws[16];
    if ((threadIdx.x & 63) == 0) ws[threadIdx.x >> 6] = s;
    __syncthreads();
    if (threadIdx.x == 0) {
        float tot = 0.0f;
#pragma unroll
        for (int w = 0; w < 16; ++w) tot += ws[w];
        out[0] = tot * (1.0f / (float)NROWS);
    }
}

extern "C" void kernel_launch(void* const* d_in, const int* in_sizes, int n_in,
                              void* d_out, int out_size, void* d_ws, size_t ws_size,
                              hipStream_t stream) {
    const float* pred = (const float*)d_in[0];
    const int* lab = (const int*)d_in[1];
    float* out = (float*)d_out;
    float* partial = (float*)d_ws;

    loss_rows_kernel<<<NBLOCKS, 256, 0, stream>>>(pred, lab, partial);
    reduce_final_kernel<<<1, 1024, 0, stream>>>(partial, NBLOCKS, out);
}